// Round 1
// baseline (8576.701 us; speedup 1.0000x reference)
//
#include <hip/hip_runtime.h>
#include <math.h>

// ============================================================================
// StackedLSTM persistent-kernel R5.
// R4 post-mortem: 6.1us/tick with all pipes ~90% idle -> latency/jitter bound.
// Structural changes:
//  - Per-wave K-sliced WAIT-A: wave wv only polls the 16 producer blocks of
//    its K-range (+1 broadcast flag for c_low), starts loads/MFMA as soon as
//    ITS slice is ready. Straggler tail = detect + 8 frag loads + 24 MFMA.
//  - B-operand (x / h_low / h_prev) loaded straight from global into VGPRs
//    (half8); LDS staging, packing and 2 syncthreads removed.
//  - Weights pre-swizzled into MFMA-fragment order in LDS: afrag reads are
//    lane-linear ds_read_b128, zero bank conflicts.
//  - RED partial layout XOR-permuted ((i16+4r)&15): writes and fused
//    reduce+gate reads are <=2-way (free). Single RED phase, 2 syncs/tick.
//  - h/c TRIPLE buffered (buf = tau%3): WAR check (wave0 polls layer+1 >= tau-1)
//    has a full tick of slack -> pre-satisfied, off critical path. Own-layer
//    WAR is implied by the 4 gate waves collectively polling all 64 own flags.
//  - c_prev carried in a register (same thread computes same (b,unit) each
//    tick); c published only for layers 0..2 (layer 3 c goes to out only).
//  - Publish: per-gate-wave sub-flags flags[l][ub][sub] (sub = batch quarter)
//    stored after that wave's own s_waitcnt vmcnt(0) drain -> no pre-flag
//    block barrier. Consumers poll 16 blocks x 4 subs = 64 lanes.
// Numerics identical to R4 (same MFMA partial order/cvt/activations).
//
// ws f32-word layout:
//   [0,       98304)  hws  f16[4][3][32][512]
//   [98304,  294912)  cws  f32[4][3][32][512]
//   [294912, 299008)  flags[4][64][4]  (16B stride per sub-flag)
// ============================================================================

#define TT 512
#define HH 512

#define CWS_OFF 98304
#define FL_OFF  294912
#define WS_ZERO_WORDS 299008

// LDS: Wf fragments [MT*8*4][64]*16B at 0, RED f32 partials after.
#define LDS_BYTES 147456   // 3*32768 (Wf) + 3*16384 (RED)

typedef _Float16 half8 __attribute__((ext_vector_type(8)));
typedef float f32x4 __attribute__((ext_vector_type(4)));

__global__ void zero_ws_k(unsigned* __restrict__ ws){
    int i = blockIdx.x*blockDim.x + threadIdx.x;
    for (; i < WS_ZERO_WORDS; i += gridDim.x*blockDim.x) ws[i] = 0u;
}

__device__ __forceinline__ float sigm(float v){ return 1.f/(1.f+__expf(-v)); }

__device__ __forceinline__ unsigned fload(const unsigned* p){
    return __hip_atomic_load(p, __ATOMIC_RELAXED, __HIP_MEMORY_SCOPE_AGENT);
}

// MT=2: layer 0 (plain LSTM, 32 gate rows). MT=3: CALSTM (40 rows, 40-47 zero).
template<int MT>
__device__ void run_loop(const float* __restrict__ x,
                         const float* __restrict__ w_ih, const float* __restrict__ w_hh,
                         const float* __restrict__ b_ih, const float* __restrict__ b_hh,
                         const float* __restrict__ ca_w, const float* __restrict__ ca_b,
                         float* __restrict__ out, float* __restrict__ ws_f,
                         char* lds, int layer, int ub)
{
    const int tid  = threadIdx.x;
    const int lane = tid & 63;
    const int wv   = tid >> 6;               // 8 waves
    const int i16  = lane & 15, qq = lane >> 4;
    const bool isGate = (wv >= 4);           // waves 4-7: h_prev MFMA + gates
    unsigned short* hws = (unsigned short*)ws_f;
    float*    cws = ws_f + CWS_OFF;
    unsigned* fl  = (unsigned*)ws_f + FL_OFF;
    float* red = (float*)(lds + MT*32768);

    // ---- one-time: weights f32 -> f16 pre-swizzled MFMA fragments in LDS ----
    // Wf[((mt*8+wvv)*4+s)*64 + lane] (16B) = W_local[mt*16+i16][wvv*128+s*32+qq*8 ..+7]
    for (int idx = tid; idx < MT*2048; idx += 512){
        const int ll  = idx & 63;
        const int s   = (idx >> 6) & 3;
        const int wvv = (idx >> 8) & 7;
        const int mt  = idx >> 11;
        const int r   = mt*16 + (ll & 15);
        const int k   = wvv*128 + s*32 + (ll >> 4)*8;
        union { _Float16 h[8]; uint4 u; } pk;
        if (MT == 3 && r >= 40){
            pk.u = make_uint4(0u,0u,0u,0u);
        } else {
            const int g = r >> 3, u = r & 7;
            const int grow = g*512 + ub*8 + u;
            const float* src;
            if (MT == 2) src = (k < 512) ? (w_ih + (size_t)grow*512 + k)
                                         : (w_hh + (size_t)grow*512 + (k - 512));
            else         src = ca_w + (size_t)(layer-1)*2560*1024 + (size_t)grow*1024 + k;
            const float4 a = *(const float4*)src;
            const float4 b = *(const float4*)(src + 4);
            pk.h[0]=(_Float16)a.x; pk.h[1]=(_Float16)a.y; pk.h[2]=(_Float16)a.z; pk.h[3]=(_Float16)a.w;
            pk.h[4]=(_Float16)b.x; pk.h[5]=(_Float16)b.y; pk.h[6]=(_Float16)b.z; pk.h[7]=(_Float16)b.w;
        }
        *(uint4*)(lds + idx*16) = pk.u;
    }

    // gate-thread invariants (tid 256..511): unit gu, batch gbl, global unit gj
    const int gtid = tid - 256;
    const int gu = gtid & 7, gbl = gtid >> 3;
    const int gj = ub*8 + gu;
    float bias[5] = {0,0,0,0,0};
    if (isGate){
        if (MT == 2){
#pragma unroll
            for (int g = 0; g < 4; ++g) bias[g] = b_ih[g*512+gj] + b_hh[g*512+gj];
        } else {
            const float* cbl = ca_b + (layer-1)*2560;
#pragma unroll
            for (int g = 0; g < 5; ++g) bias[g] = cbl[g*512+gj];
            bias[1] += 1.f; bias[2] += 1.f;   // fold +1.0 of f_prev/f_low
        }
    }

    // poll pointers
    const unsigned* pollp  = nullptr;  // per-lane: 16 blocks x 4 subs of my K-slice
    const unsigned* belowp = nullptr;  // broadcast: below-block ub, sub = my batch quarter
    const unsigned* warp_p = nullptr;  // WAR: layer+1, block=lane, sub 0
    if (isGate){
        pollp = fl + ((layer*64 + ((wv-4)*16 + (lane>>2)))*4 + (lane&3))*4;
        if (MT == 3) belowp = fl + (((layer-1)*64 + ub)*4 + (wv-4))*4;
    } else if (MT == 3){
        pollp = fl + (((layer-1)*64 + (wv*16 + (lane>>2)))*4 + (lane&3))*4;
    }
    if (wv == 0 && layer < 3) warp_p = fl + (((layer+1)*64 + lane)*4 + 0)*4;

    // pre-publish: idle ticks 0..layer-1 vacuously complete (all 4 subs)
    if (tid < 4)
        __hip_atomic_store(fl + ((layer*64+ub)*4 + tid)*4, (unsigned)layer,
                           __ATOMIC_RELAXED, __HIP_MEMORY_SCOPE_AGENT);
    __syncthreads();    // weights staged before first MFMA

    float creg = 0.f;   // register-carried c(t-1) for this (gu,gbl)

    for (int tau = layer; tau < TT + layer; ++tau){
        const int t  = tau - layer;
        const int pb = tau % 3;            // publish buffer
        const int qb = (tau + 2) % 3;      // read buffer = (tau-1)%3

        // ---- WAR, one tick of slack -> normally a single satisfied check ----
        if (warp_p){
            const unsigned need = (tau >= 1) ? (unsigned)(tau - 1) : 0u;
            for (;;){
                if (__all((int)(fload(warp_p) >= need))) break;
                __builtin_amdgcn_s_sleep(1);
            }
        }

        // ---- WAIT-A (per wave, K-sliced) + acquire ----
        if (MT == 3 && !isGate){
            for (;;){
                if (__all((int)(fload(pollp) >= (unsigned)tau))) break;
                __builtin_amdgcn_s_sleep(1);
            }
            __builtin_amdgcn_fence(__ATOMIC_ACQUIRE, "agent");
        }
        if (isGate){
            if (MT == 3){
                for (;;){
                    const unsigned v1 = fload(pollp);
                    const unsigned v2 = fload(belowp);
                    if (__all((int)(v1 >= (unsigned)tau && v2 >= (unsigned)tau))) break;
                    __builtin_amdgcn_s_sleep(1);
                }
            } else {
                for (;;){
                    if (__all((int)(fload(pollp) >= (unsigned)tau))) break;
                    __builtin_amdgcn_s_sleep(1);
                }
            }
            __builtin_amdgcn_fence(__ATOMIC_ACQUIRE, "agent");
        }

        // c_low early-issue (latency hidden under bfrag loads + MFMA + syncs)
        float clov = 0.f;
        if (isGate && MT == 3)
            clov = cws[(size_t)(((layer-1)*3 + qb)*32 + gbl)*512 + gj];

        // ---- B-fragments direct from global + MFMA (K-slice of this wave) ----
        f32x4 acc[MT][2];
#pragma unroll
        for (int mt = 0; mt < MT; ++mt){ acc[mt][0] = (f32x4){0,0,0,0}; acc[mt][1] = (f32x4){0,0,0,0}; }

        if (MT == 2 && !isGate){
            // layer 0, k<512: x_t (no dependency, no wait)
            half8 bf0[4], bf1[4];
#pragma unroll
            for (int s = 0; s < 4; ++s){
                const int k = wv*128 + s*32 + qq*8;
                const float* x0 = x + ((size_t)i16*TT + t)*HH + k;
                const float* x1 = x + ((size_t)(16+i16)*TT + t)*HH + k;
                const float4 a0 = *(const float4*)x0, a1 = *(const float4*)(x0+4);
                const float4 c0 = *(const float4*)x1, c1 = *(const float4*)(x1+4);
                half8 h0, h1;
                h0[0]=(_Float16)a0.x; h0[1]=(_Float16)a0.y; h0[2]=(_Float16)a0.z; h0[3]=(_Float16)a0.w;
                h0[4]=(_Float16)a1.x; h0[5]=(_Float16)a1.y; h0[6]=(_Float16)a1.z; h0[7]=(_Float16)a1.w;
                h1[0]=(_Float16)c0.x; h1[1]=(_Float16)c0.y; h1[2]=(_Float16)c0.z; h1[3]=(_Float16)c0.w;
                h1[4]=(_Float16)c1.x; h1[5]=(_Float16)c1.y; h1[6]=(_Float16)c1.z; h1[7]=(_Float16)c1.w;
                bf0[s] = h0; bf1[s] = h1;
            }
#pragma unroll
            for (int s = 0; s < 4; ++s)
#pragma unroll
                for (int mt = 0; mt < MT; ++mt){
                    const half8 af = *(const half8*)(lds + (((mt*8 + wv)*4 + s)*64 + lane)*16);
                    acc[mt][0] = __builtin_amdgcn_mfma_f32_16x16x32_f16(af, bf0[s], acc[mt][0], 0, 0, 0);
                    acc[mt][1] = __builtin_amdgcn_mfma_f32_16x16x32_f16(af, bf1[s], acc[mt][1], 0, 0, 0);
                }
        } else {
            // h_low (low waves, MT3) or h_prev (gate waves), f16 direct
            const unsigned short* hsrc = isGate
                ? hws + (size_t)((layer*3 + qb)*32)*512
                : hws + (size_t)(((layer-1)*3 + qb)*32)*512;
            const int kb = (wv & 3)*128;
            half8 bf0[4], bf1[4];
#pragma unroll
            for (int s = 0; s < 4; ++s){
                const int k = kb + s*32 + qq*8;
                bf0[s] = *(const half8*)(hsrc + (size_t)i16*512 + k);
                bf1[s] = *(const half8*)(hsrc + (size_t)(16+i16)*512 + k);
            }
#pragma unroll
            for (int s = 0; s < 4; ++s)
#pragma unroll
                for (int mt = 0; mt < MT; ++mt){
                    const half8 af = *(const half8*)(lds + (((mt*8 + wv)*4 + s)*64 + lane)*16);
                    acc[mt][0] = __builtin_amdgcn_mfma_f32_16x16x32_f16(af, bf0[s], acc[mt][0], 0, 0, 0);
                    acc[mt][1] = __builtin_amdgcn_mfma_f32_16x16x32_f16(af, bf1[s], acc[mt][1], 0, 0, 0);
                }
        }

        __syncthreads();   // sync1: prev-tick RED reads complete (WAR on RED)

        // ---- K-partials, XOR-permuted layout: <=2-way banks both sides ----
#pragma unroll
        for (int mt = 0; mt < MT; ++mt)
#pragma unroll
            for (int nt = 0; nt < 2; ++nt)
#pragma unroll
                for (int r = 0; r < 4; ++r)
                    red[((((wv*MT + mt)*2 + nt)*4 + r)*4 + qq)*16 + ((i16 + 4*r)&15)] = acc[mt][nt][r];

        __syncthreads();   // sync2: partials visible

        // ---- fused reduce + gates + publish (gate waves only) ----
        if (isGate){
            const int NG = (MT == 2) ? 4 : 5;
            float mg[5];
#pragma unroll
            for (int g = 0; g < 5; ++g){
                if (g >= NG) break;
                const int m = g*8 + gu, mt2 = m >> 4, mr = m & 15, q2 = mr >> 2, r2 = mr & 3;
                const int nt2 = gbl >> 4, i2 = gbl & 15;
                const int base = (((mt2*2 + nt2)*4 + r2)*4 + q2)*16 + ((i2 + 4*r2)&15);
                float sm = 0.f;
#pragma unroll
                for (int kv = 0; kv < 8; ++kv) sm += red[base + kv*MT*512];
                mg[g] = sm + bias[g];
            }
            float cval, hval;
            if (MT == 2){
                cval = sigm(mg[0])*tanhf(mg[2]) + sigm(mg[1])*creg;
                hval = sigm(mg[3])*tanhf(cval);
            } else {
                cval = creg*sigm(mg[1]) + clov*sigm(mg[2]) + tanhf(mg[3])*sigm(mg[0]);
                hval = sigm(mg[4])*tanhf(cval);
            }
            creg = cval;

            const float hnb = __shfl_down(hval, 1);
            if (layer < 3)
                __hip_atomic_store(&cws[(size_t)((layer*3 + pb)*32 + gbl)*512 + gj], cval,
                                   __ATOMIC_RELAXED, __HIP_MEMORY_SCOPE_AGENT);
            if ((gu & 1) == 0){
                union { _Float16 h2[2]; unsigned u; } pk;
                pk.h2[0] = (_Float16)hval; pk.h2[1] = (_Float16)hnb;
                __hip_atomic_store((unsigned*)(hws + (size_t)((layer*3 + pb)*32 + gbl)*512 + gj),
                                   pk.u, __ATOMIC_RELAXED, __HIP_MEMORY_SCOPE_AGENT);
            }
            asm volatile("s_waitcnt vmcnt(0)" ::: "memory");   // data at coherence pt
            if (lane == 0)
                __hip_atomic_store(fl + ((layer*64 + ub)*4 + (wv-4))*4, (unsigned)(tau + 1),
                                   __ATOMIC_RELAXED, __HIP_MEMORY_SCOPE_AGENT);

            // outputs (not consumed on-device; after flag, off critical path)
            if (MT == 3 && layer == 3){
                const size_t pos = ((size_t)gbl*TT + t)*HH + gj;
                out[pos]           = hval;
                out[8388608 + pos] = cval;
                if (t == TT-1){
                    out[16777216 + (size_t)gbl*HH + gj] = hval;
                    out[16793600 + (size_t)gbl*HH + gj] = cval;
                }
            }
        }
    }
    // No sentinel: all poll targets are <= real final flag values
    // (own: TT+layer-1 <= TT+layer; below: TT+layer-1 <= TT+layer-1+1; WAR: TT+l-2).
}

__global__ __launch_bounds__(512) void persist_k(
    const float* __restrict__ x, const float* __restrict__ w_ih,
    const float* __restrict__ w_hh, const float* __restrict__ b_ih,
    const float* __restrict__ b_hh, const float* __restrict__ ca_w,
    const float* __restrict__ ca_b, float* __restrict__ out,
    float* __restrict__ ws_f)
{
    extern __shared__ char lds[];
    const int bx = blockIdx.x;
    const int layer = bx >> 6, ub = bx & 63;
    if (layer == 0) run_loop<2>(x, w_ih, w_hh, b_ih, b_hh, ca_w, ca_b, out, ws_f, lds, layer, ub);
    else            run_loop<3>(x, w_ih, w_hh, b_ih, b_hh, ca_w, ca_b, out, ws_f, lds, layer, ub);
}

extern "C" void kernel_launch(void* const* d_in, const int* in_sizes, int n_in,
                              void* d_out, int out_size, void* d_ws, size_t ws_size,
                              hipStream_t stream)
{
    const float* x    = (const float*)d_in[0];
    const float* w_ih = (const float*)d_in[1];
    const float* w_hh = (const float*)d_in[2];
    const float* b_ih = (const float*)d_in[3];
    const float* b_hh = (const float*)d_in[4];
    const float* ca_w = (const float*)d_in[5];
    const float* ca_b = (const float*)d_in[6];
    float* out = (float*)d_out;
    float* ws  = (float*)d_ws;

    (void)hipFuncSetAttribute((const void*)persist_k,
                              hipFuncAttributeMaxDynamicSharedMemorySize, LDS_BYTES);
    hipLaunchKernelGGL(zero_ws_k, dim3(64), dim3(256), 0, stream, (unsigned*)ws);
    hipLaunchKernelGGL(persist_k, dim3(256), dim3(512), LDS_BYTES, stream,
                       x, w_ih, w_hh, b_ih, b_hh, ca_w, ca_b, out, ws);
}

// Round 2
// 3157.218 us; speedup vs baseline: 2.7165x; 2.7165x over previous
//
#include <hip/hip_runtime.h>
#include <math.h>

// ============================================================================
// StackedLSTM persistent-kernel R6 = R4 structure + proven R5 grafts.
// R5 post-mortem: direct-global B loads + 8 fences/tick + 8 polling waves
// tripled time (16.6us/tick) -> tick is communication-latency bound; keep
// R4's cooperative LDS staging, single acquire fence, single flag per block.
// Grafts (validated in R5: absmax unchanged, SQ_LDS_BANK_CONFLICT -> 0):
//   - RED partials XOR-permuted ((i16+4r)&15) + fused reduce+gates: removes
//     the 4-way write / 8-way gate-read conflicts and one LDS phase+2 syncs.
//   - h/c TRIPLE buffered (pb=tau%3, qb=(tau-1)%3): WAR needs upper flags
//     >= tau-1 (full tick of slack, pre-satisfied) -> WAIT-B off crit path
//     (wave-2 poll at tick top), pre-publish barrier removed.
//   - c_prev carried in a register; cws published only for layers 0..2.
//
// ws f32-word layout:
//   [0,       98304)  hws  f16[4][3][32][512]
//   [98304,  294912)  cws  f32[4][3][32][512]
//   [294912, 295936)  flags[4][64]  (16B stride)
// ============================================================================

#define TT 512
#define HH 512
#define ROWP 1032                    // padded LDS row length in f16
#define W_OFF 0
#define A_OFF 82560                  // 40*ROWP*2
#define RED_OFF A_OFF                // aliases A region (used after dots done)
#define LDS_BYTES (A_OFF + 66048)    // 148608 B -> 1 block/CU

#define CWS_OFF 98304
#define FL_OFF  294912
#define WS_ZERO_WORDS (FL_OFF + 1024)

typedef _Float16 half8 __attribute__((ext_vector_type(8)));
typedef float f32x4 __attribute__((ext_vector_type(4)));

__global__ void zero_ws_k(unsigned* __restrict__ ws){
    int i = blockIdx.x*blockDim.x + threadIdx.x;
    for (; i < WS_ZERO_WORDS; i += gridDim.x*blockDim.x) ws[i] = 0u;
}

__device__ __forceinline__ float sigm(float v){ return 1.f/(1.f+__expf(-v)); }

// Wave-cooperative poll: lane i watches flags[L][i] until all >= need.
__device__ __forceinline__ void poll_layer(const unsigned* fl, int L, unsigned need){
    const int i = threadIdx.x & 63;
    const unsigned* p = fl + (L*64 + i)*4;
    for (;;){
        const unsigned v = __hip_atomic_load(p, __ATOMIC_RELAXED, __HIP_MEMORY_SCOPE_AGENT);
        if (__all((int)(v >= need))) break;
        __builtin_amdgcn_s_sleep(2);
    }
}

// MT=2: layer 0 (LSTM, 32 gate-rows). MT=3: CALSTM (40 rows, rows 40-47 junk).
template<int MT>
__device__ void run_loop(const float* __restrict__ x, const float* __restrict__ b_ih,
                         const float* __restrict__ b_hh, const float* __restrict__ ca_b,
                         float* __restrict__ out, float* __restrict__ ws_f,
                         char* lds, int layer, int ub)
{
    const int tid  = threadIdx.x;
    const int lane = tid & 63;
    const int wv   = tid >> 6;              // wave id 0..7 = K-eighth
    const int i16  = lane & 15, qq = lane >> 4;
    unsigned short* hws = (unsigned short*)ws_f;   // f16[l][buf][b][512]
    float*    cws = ws_f + CWS_OFF;                // f32[l][buf][b][512]
    unsigned* fl  = (unsigned*)ws_f + FL_OFF;
    float* red = (float*)(lds + RED_OFF);

    // gate-thread invariants (tid<256): unit gu, batch gb, global unit gj
    const int gu = tid & 7, gb = tid >> 3, gj = ub*8 + gu;
    float bias[5] = {0,0,0,0,0};
    if (tid < 256){
        if (MT == 2){
#pragma unroll
            for (int g = 0; g < 4; ++g) bias[g] = b_ih[g*512+gj] + b_hh[g*512+gj];
        } else {
            const float* cbl = ca_b + (layer-1)*2560;
#pragma unroll
            for (int g = 0; g < 5; ++g) bias[g] = cbl[g*512+gj];
            bias[1] += 1.f; bias[2] += 1.f;   // fold the +1.0 of f_prev/f_low
        }
    }
    // initial publish: idle ticks 0..layer-1 are vacuously complete
    if (tid == 0 && layer > 0)
        __hip_atomic_store(fl + (layer*64+ub)*4, (unsigned)layer,
                           __ATOMIC_RELAXED, __HIP_MEMORY_SCOPE_AGENT);

    float creg = 0.f;   // register-carried c(t-1) for this (gu,gb)

    for (int tau = layer; tau < TT + layer; ++tau){
        const int t  = tau - layer;
        const int pb = tau % 3;           // publish buffer
        const int qb = (tau + 2) % 3;     // read buffer = (tau-1)%3

        // ---- x prefetch (layer 0, x-half threads) — no dependency on flags
        uint4 xpk[8];
        if (MT == 2 && (tid & 127) < 64){
#pragma unroll
            for (int it = 0; it < 8; ++it){
                const int cidx = tid + it*512;
                const int b = cidx >> 7, kc = (cidx & 127) << 3;   // kc < 512
                const float* xs = x + ((size_t)b*TT + t)*HH + kc;
                const float4 a = *(const float4*)xs;
                const float4 c = *(const float4*)(xs + 4);
                union { _Float16 h[8]; uint4 u; } pk;
                pk.h[0]=(_Float16)a.x; pk.h[1]=(_Float16)a.y;
                pk.h[2]=(_Float16)a.z; pk.h[3]=(_Float16)a.w;
                pk.h[4]=(_Float16)c.x; pk.h[5]=(_Float16)c.y;
                pk.h[6]=(_Float16)c.z; pk.h[7]=(_Float16)c.w;
                xpk[it] = pk.u;
            }
        }

        // ---- WAIT-A (RAW, tick tau-1 producers) + WAIT-B (WAR, slack=1 tick)
        if (wv == 0)                    poll_layer(fl, layer,   (unsigned)tau);
        else if (wv == 1 && MT == 3)    poll_layer(fl, layer-1, (unsigned)tau);
        else if (wv == 2 && layer < 3)  poll_layer(fl, layer+1,
                                            (tau > 0) ? (unsigned)(tau-1) : 0u);
        if (wv == 0) __builtin_amdgcn_fence(__ATOMIC_ACQUIRE, "agent"); // inv only
        __syncthreads();                                  // S1

        // ---- c_low prefetch (fresh after inv, used much later)
        float clov = 0.f;
        if (MT == 3 && tid < 256)
            clov = cws[((layer-1)*3+qb)*16384 + gb*512 + gj];

        // ---- stage A = [x_t | h_low ; h_prev] into LDS (f16) ----
        if (MT == 2){
            if ((tid & 127) < 64){
#pragma unroll
                for (int it = 0; it < 8; ++it){
                    const int cidx = tid + it*512;
                    const int b = cidx >> 7, kc = (cidx & 127) << 3;
                    *(uint4*)(lds + A_OFF + (size_t)(b*ROWP + kc)*2) = xpk[it];
                }
            } else {
                const unsigned short* hprev = hws + (layer*3+qb)*16384;
#pragma unroll
                for (int it = 0; it < 8; ++it){
                    const int cidx = tid + it*512;
                    const int b = cidx >> 7, kc = (cidx & 127) << 3;  // kc>=512
                    const uint4 v = *(const uint4*)(hprev + b*512 + (kc - 512));
                    *(uint4*)(lds + A_OFF + (size_t)(b*ROWP + kc)*2) = v;
                }
            }
        } else {
            const unsigned short* hlow  = hws + ((layer-1)*3+qb)*16384;
            const unsigned short* hprev = hws + (layer*3+qb)*16384;
#pragma unroll
            for (int it = 0; it < 8; ++it){
                const int cidx = tid + it*512;
                const int b = cidx >> 7, kc = (cidx & 127) << 3;
                const uint4 v = (kc < 512) ? *(const uint4*)(hlow  + b*512 + kc)
                                           : *(const uint4*)(hprev + b*512 + (kc - 512));
                *(uint4*)(lds + A_OFF + (size_t)(b*ROWP + kc)*2) = v;
            }
        }
        __syncthreads();                                  // S2

        // ---- MFMA dots: this wave covers K-range [wv*128, wv*128+128) ----
        f32x4 acc[MT][2];
#pragma unroll
        for (int mt = 0; mt < MT; ++mt){ acc[mt][0] = (f32x4){0,0,0,0}; acc[mt][1] = (f32x4){0,0,0,0}; }
#pragma unroll
        for (int s = 0; s < 4; ++s){
            const int koff = wv*128 + s*32 + qq*8;
            half8 bfrag0 = *(const half8*)(lds + A_OFF + ((0*16 + i16)*ROWP + koff)*2);
            half8 bfrag1 = *(const half8*)(lds + A_OFF + ((1*16 + i16)*ROWP + koff)*2);
#pragma unroll
            for (int mt = 0; mt < MT; ++mt){
                half8 afrag = *(const half8*)(lds + W_OFF + ((mt*16 + i16)*ROWP + koff)*2);
                acc[mt][0] = __builtin_amdgcn_mfma_f32_16x16x32_f16(afrag, bfrag0, acc[mt][0], 0, 0, 0);
                acc[mt][1] = __builtin_amdgcn_mfma_f32_16x16x32_f16(afrag, bfrag1, acc[mt][1], 0, 0, 0);
            }
        }
        __syncthreads();            // S3: A reads done; RED aliases A

        // ---- K-partials, XOR-permuted: writes and reads <=2-way banks ----
#pragma unroll
        for (int mt = 0; mt < MT; ++mt)
#pragma unroll
            for (int nt = 0; nt < 2; ++nt)
#pragma unroll
                for (int r = 0; r < 4; ++r)
                    red[((((wv*MT + mt)*2 + nt)*4 + r)*4 + qq)*16 + ((i16 + 4*r)&15)] = acc[mt][nt][r];
        __syncthreads();                                  // S4

        // ---- fused reduce + gates (tid<256) ----
        float hval = 0.f, cval = 0.f;
        if (tid < 256){
            const int NG = (MT == 2) ? 4 : 5;
            float mg[5];
#pragma unroll
            for (int g = 0; g < NG; ++g){
                const int m = g*8 + gu, mt2 = m >> 4, mr = m & 15, q2 = mr >> 2, r2 = mr & 3;
                const int nt2 = gb >> 4, i2 = gb & 15;
                const int base = (((mt2*2 + nt2)*4 + r2)*4 + q2)*16 + ((i2 + 4*r2)&15);
                float sm = 0.f;
#pragma unroll
                for (int kv = 0; kv < 8; ++kv) sm += red[base + kv*MT*512];
                mg[g] = sm + bias[g];
            }
            if (MT == 2){
                cval = sigm(mg[0])*tanhf(mg[2]) + sigm(mg[1])*creg;
                hval = sigm(mg[3])*tanhf(cval);
            } else {
                cval = creg*sigm(mg[1]) + clov*sigm(mg[2]) + tanhf(mg[3])*sigm(mg[0]);
                hval = sigm(mg[4])*tanhf(cval);
            }
            creg = cval;
        }

        // ---- publish h (packed f16x2, write-through) and c (f32) ----
        const float hnb = __shfl_down(hval, 1);
        if (tid < 256){
            if (layer < 3)
                __hip_atomic_store(&cws[(layer*3+pb)*16384 + gb*512 + gj], cval,
                                   __ATOMIC_RELAXED, __HIP_MEMORY_SCOPE_AGENT);
            if ((gu & 1) == 0){
                union { _Float16 h2[2]; unsigned u; } pk;
                pk.h2[0] = (_Float16)hval; pk.h2[1] = (_Float16)hnb;
                __hip_atomic_store((unsigned*)(hws + (layer*3+pb)*16384 + gb*512 + gj),
                                   pk.u, __ATOMIC_RELAXED, __HIP_MEMORY_SCOPE_AGENT);
            }
        }
        asm volatile("s_waitcnt vmcnt(0)" ::: "memory");   // stores at coherence pt
        __syncthreads();                                  // S5
        if (tid == 0)
            __hip_atomic_store(fl + (layer*64+ub)*4, (unsigned)(tau + 1),
                               __ATOMIC_RELAXED, __HIP_MEMORY_SCOPE_AGENT);

        // ---- outputs (not consumed on-device; after publish, off crit path)
        if (layer == 3 && tid < 256){
            const size_t pos = ((size_t)gb*TT + t)*HH + gj;
            out[pos]           = hval;
            out[8388608 + pos] = cval;
            if (t == TT-1){
                out[16777216 + (size_t)gb*HH + gj] = hval;
                out[16793600 + (size_t)gb*HH + gj] = cval;
            }
        }
    }
    // cover all future waits by neighbors
    if (tid == 0)
        __hip_atomic_store(fl + (layer*64+ub)*4, 0x7FFFFFFFu,
                           __ATOMIC_RELAXED, __HIP_MEMORY_SCOPE_AGENT);
}

__global__ __launch_bounds__(512) void persist_k(
    const float* __restrict__ x, const float* __restrict__ w_ih,
    const float* __restrict__ w_hh, const float* __restrict__ b_ih,
    const float* __restrict__ b_hh, const float* __restrict__ ca_w,
    const float* __restrict__ ca_b, float* __restrict__ out,
    float* __restrict__ ws_f)
{
    extern __shared__ char lds[];
    const int bx = blockIdx.x;
    const int layer = bx >> 6, ub = bx & 63;
    const int tid = threadIdx.x;
    const int rows = (layer == 0) ? 32 : 40;

    // one-time: weights fp32 -> f16 into LDS. local row r=g*8+u maps to
    // global gate-matrix row g*512 + ub*8 + u.
    for (int idx = tid; idx < rows*256; idx += 512){
        const int r = idx >> 8, k4 = (idx & 255) * 4;
        const int g = r >> 3, u = r & 7;
        const int grow = g*512 + ub*8 + u;
        const float* src;
        if (layer == 0) src = (k4 < 512) ? (w_ih + (size_t)grow*512 + k4)
                                         : (w_hh + (size_t)grow*512 + (k4 - 512));
        else            src = ca_w + (size_t)(layer-1)*2560*1024 + (size_t)grow*1024 + k4;
        const float4 v = *(const float4*)src;
        union { _Float16 h[4]; uint2 u2; } pk;
        pk.h[0]=(_Float16)v.x; pk.h[1]=(_Float16)v.y;
        pk.h[2]=(_Float16)v.z; pk.h[3]=(_Float16)v.w;
        *(uint2*)(lds + W_OFF + ((size_t)(r*ROWP + k4))*2) = pk.u2;
    }
    // first tick's S1 __syncthreads orders weight-load before MFMA use.
    if (layer == 0) run_loop<2>(x, b_ih, b_hh, ca_b, out, ws_f, lds, layer, ub);
    else            run_loop<3>(x, b_ih, b_hh, ca_b, out, ws_f, lds, layer, ub);
}

extern "C" void kernel_launch(void* const* d_in, const int* in_sizes, int n_in,
                              void* d_out, int out_size, void* d_ws, size_t ws_size,
                              hipStream_t stream)
{
    const float* x    = (const float*)d_in[0];
    const float* w_ih = (const float*)d_in[1];
    const float* w_hh = (const float*)d_in[2];
    const float* b_ih = (const float*)d_in[3];
    const float* b_hh = (const float*)d_in[4];
    const float* ca_w = (const float*)d_in[5];
    const float* ca_b = (const float*)d_in[6];
    float* out = (float*)d_out;
    float* ws  = (float*)d_ws;

    (void)hipFuncSetAttribute((const void*)persist_k,
                              hipFuncAttributeMaxDynamicSharedMemorySize, LDS_BYTES);
    hipLaunchKernelGGL(zero_ws_k, dim3(64), dim3(256), 0, stream, (unsigned*)ws);
    hipLaunchKernelGGL(persist_k, dim3(256), dim3(512), LDS_BYTES, stream,
                       x, w_ih, w_hh, b_ih, b_hh, ca_w, ca_b, out, ws);
}